// Round 13
// baseline (2033.260 us; speedup 1.0000x reference)
//
#include <hip/hip_runtime.h>

#define NPOS 65536   // 64 batches * 32 * 32 positions
#define NE   121     // 11*11 tensor entries
#define NP   6       // p-rows per half (conv kernels)
#define NPP  4       // p-rows per third for dual conv1x1 (4+4+3)

// direct HBM->LDS (no VGPR staging; dest = wave-uniform base + lane*16)
__device__ __forceinline__ void gload_lds16(const float* g, float* l) {
  __builtin_amdgcn_global_load_lds(
      (const __attribute__((address_space(1))) void*)g,
      (__attribute__((address_space(3))) void*)l, 16, 0, 0);
}

// ------------------------------------------------------------------
// f0 v4: R8 slab pipeline + FULL Y[11][11] per thread (no p-split).
// R12 analysis: issue-bound; p-split duplicated X/V ds_reads (2x) and
// U (1.33x) for the same FLOPs. Full-Y = R6-proven register shape
// (168 VGPR, no spill at (256,1)). Grid 2048 = (b,h). 8 waves/CU.
// ------------------------------------------------------------------
__global__ __launch_bounds__(256, 1)
void f0_kernel(const float* __restrict__ x, const float* __restrict__ U,
               const float* __restrict__ V, float* __restrict__ y,
               float* __restrict__ psum, float* __restrict__ psq) {
  __shared__ float Xb[16384];   // 2 x 8192 (64KB) double-buffered X slab
  __shared__ float su[1728];    // [tap][m][12] : p 0..10 (+1 pad)
  __shared__ float sv[1728];    // [tap][n][12] : q 0..10 (+1 pad)

  int bid = blockIdx.x;
  int wg  = (bid & 7) * 256 + (bid >> 3);     // bijective, 2048 % 8 == 0
  int row = wg;                               // (b,h)
  int b = row >> 5, h = row & 31;
  int t = threadIdx.x;
  int s = t >> 5, w = t & 31;

  int hlo = (h == 0) ? 0 : h - 1;
  int hhi = (h == 31) ? 31 : h + 1;
  int nh = hhi - hlo + 1;
  int nslab = 8 * nh;

  float Y[11][11];
#pragma unroll
  for (int p = 0; p < 11; ++p)
#pragma unroll
    for (int q = 0; q < 11; ++q) Y[p][q] = 0.f;

  auto stageUV = [&](int c) {
    for (int idx = t; idx < 1728; idx += 256) {     // su[tap*192 + m*12 + p]
      int tap = idx / 192, r = idx - tap * 192;
      int m = r / 12, pp = r - m * 12;
      su[idx] = (pp < 11) ? U[(c * 9 + tap) * 176 + pp * 16 + m] : 0.f;
    }
    for (int idx = t; idx < 1728; idx += 256) {     // sv[tap*192 + n*12 + q]
      int tap = idx / 192, r = idx - tap * 192;
      int n = r / 12, q = r - n * 12;
      sv[idx] = (q < 11) ? V[(c * 9 + tap) * 176 + q * 16 + n] : 0.f;
    }
  };

  auto issueX = [&](int k) {
    int c = k / nh, hi = hlo + k % nh;
    const float* base = x + ((size_t)(b * 8 + c) << 18) + hi * 32;
    float* buf = &Xb[(k & 1) * 8192];
    int wv = t >> 6, ln = t & 63;
#pragma unroll
    for (int kk = 0; kk < 8; ++kk) {
      int chunk = wv * 8 + kk;                      // wave-uniform
      int mn = chunk * 8 + (ln >> 3);
      gload_lds16(base + (size_t)mn * 1024 + (ln & 7) * 4, buf + chunk * 256);
    }
  };

  stageUV(0);
  issueX(0);

  for (int k = 0; k < nslab; ++k) {
    asm volatile("s_waitcnt vmcnt(0)" ::: "memory"); // slab k landed
    __syncthreads();
    if (k + 1 < nslab) issueX(k + 1);

    const float* Xt = &Xb[(k & 1) * 8192];
    int c = k / nh, hi = hlo + k % nh;
    int tapbase = (hi - h + 1) * 3;
#pragma unroll
    for (int j = 0; j < 3; ++j) {
      int wj = w + j - 1;
      if ((unsigned)wj < 32u) {
        int tap = tapbase + j;
        const float* suT = &su[tap * 192];
        const float* svT = &sv[tap * 192];
        float A0[11], A1[11];
#pragma unroll
        for (int p = 0; p < 11; ++p) { A0[p] = 0.f; A1[p] = 0.f; }
#pragma unroll
        for (int m = 0; m < 16; ++m) {
          float x0 = Xt[(m * 16 + 2 * s) * 32 + wj];
          float x1 = Xt[(m * 16 + 2 * s + 1) * 32 + wj];
          float4 u0 = *(const float4*)&suT[m * 12 + 0];   // broadcast b128
          float4 u1 = *(const float4*)&suT[m * 12 + 4];
          float4 u2 = *(const float4*)&suT[m * 12 + 8];
          float up[11] = { u0.x, u0.y, u0.z, u0.w,
                           u1.x, u1.y, u1.z, u1.w,
                           u2.x, u2.y, u2.z };
#pragma unroll
          for (int p = 0; p < 11; ++p) {
            A0[p] += up[p] * x0;
            A1[p] += up[p] * x1;
          }
        }
#pragma unroll
        for (int nn = 0; nn < 2; ++nn) {
          const float* vb = &svT[(2 * s + nn) * 12];
          float4 v0 = *(const float4*)&vb[0];
          float4 v1 = *(const float4*)&vb[4];
          float4 v2 = *(const float4*)&vb[8];
          float vq[11] = { v0.x, v0.y, v0.z, v0.w,
                           v1.x, v1.y, v1.z, v1.w,
                           v2.x, v2.y, v2.z };
          const float* Ax = nn ? A1 : A0;    // nn is unroll-static
#pragma unroll
          for (int p = 0; p < 11; ++p)
#pragma unroll
            for (int q = 0; q < 11; ++q)
              Y[p][q] += Ax[p] * vq[q];
        }
      }
    }
    if (k + 1 < nslab && (k % nh) == nh - 1) {    // next slab = new channel
      __syncthreads();
      stageUV(c + 1);
    }
  }

  // epilogue: reduce over s, write y, fused stats partials per (b,h) row
  int posb = ((b << 5) + h) << 5;
#pragma unroll
  for (int p = 0; p < 11; ++p) {
    __syncthreads();
#pragma unroll
    for (int q = 0; q < 11; ++q) Xb[t * 11 + q] = Y[p][q];
    __syncthreads();
    for (int rep = 0; rep < 2; ++rep) {
      int idx = rep * 256 + t;
      if (idx < 352) {                      // full 32-lane groups only
        int qq = idx >> 5, w2 = idx & 31;
        float v = 0.f;
#pragma unroll
        for (int s2 = 0; s2 < 8; ++s2) v += Xb[(s2 * 32 + w2) * 11 + qq];
        int e = p * 11 + qq;
        y[(size_t)e * NPOS + posb + w2] = v;
        float sm = v, sq = v * v;
#pragma unroll
        for (int d = 16; d > 0; d >>= 1) {
          sm += __shfl_down(sm, d, 32);
          sq += __shfl_down(sq, d, 32);
        }
        if (w2 == 0) {
          psum[(size_t)e * 2048 + row] = sm;
          psq [(size_t)e * 2048 + row] = sq;
        }
      }
    }
  }
}

// finalize f0 stats: 121 blocks sum 2048 row-partials -> scale/shift
__global__ __launch_bounds__(256)
void f0_stats_final(const float* __restrict__ psum, const float* __restrict__ psq,
                    const float* __restrict__ g, const float* __restrict__ bb,
                    float* __restrict__ sc, float* __restrict__ sh) {
  int e = blockIdx.x, t = threadIdx.x;
  float s = 0.f, s2 = 0.f;
  for (int i = t; i < 2048; i += 256) {
    s  += psum[(size_t)e * 2048 + i];
    s2 += psq [(size_t)e * 2048 + i];
  }
#pragma unroll
  for (int o = 32; o > 0; o >>= 1) {
    s  += __shfl_down(s, o);
    s2 += __shfl_down(s2, o);
  }
  __shared__ float ls[8];
  int wid = t >> 6;
  if ((t & 63) == 0) { ls[wid] = s; ls[4 + wid] = s2; }
  __syncthreads();
  if (t == 0) {
    float ss  = ls[0] + ls[1] + ls[2] + ls[3];
    float ss2 = ls[4] + ls[5] + ls[6] + ls[7];
    float mu  = ss  * (1.f / 65536.f);
    float var = ss2 * (1.f / 65536.f) - mu * mu;
    float sca = g[e] * rsqrtf(var + 1e-5f);
    sc[e] = sca;
    sh[e] = bb[e] - mu * sca;
  }
}

// ------------------------------------------------------------------
// Widened TBN stats: 484-block quarter-entry partial + tiny finalize.
// ------------------------------------------------------------------
__global__ __launch_bounds__(256)
void stats_partial(const float* __restrict__ raw, float* __restrict__ part) {
  int blk = blockIdx.x;
  int e = blk >> 2, qt = blk & 3;
  const float4* p = (const float4*)(raw + (size_t)e * NPOS) + qt * 4096;
  int t = threadIdx.x;
  float s = 0.f, s2 = 0.f;
  for (int i = t; i < 4096; i += 256) {
    float4 v = p[i];
    s  += v.x + v.y + v.z + v.w;
    s2 += v.x * v.x + v.y * v.y + v.z * v.z + v.w * v.w;
  }
#pragma unroll
  for (int o = 32; o > 0; o >>= 1) {
    s  += __shfl_down(s, o);
    s2 += __shfl_down(s2, o);
  }
  __shared__ float ls[8];
  int wid = t >> 6;
  if ((t & 63) == 0) { ls[wid] = s; ls[4 + wid] = s2; }
  __syncthreads();
  if (t == 0) {
    part[blk]       = ls[0] + ls[1] + ls[2] + ls[3];
    part[484 + blk] = ls[4] + ls[5] + ls[6] + ls[7];
  }
}

__global__ void stats_final(const float* __restrict__ part, const float* __restrict__ g,
                            const float* __restrict__ bb, float* __restrict__ sc,
                            float* __restrict__ sh) {
  int e = threadIdx.x;
  if (e < 121) {
    float s  = part[e * 4] + part[e * 4 + 1] + part[e * 4 + 2] + part[e * 4 + 3];
    float s2 = part[484 + e * 4] + part[484 + e * 4 + 1] +
               part[484 + e * 4 + 2] + part[484 + e * 4 + 3];
    float mu  = s  * (1.f / 65536.f);
    float var = s2 * (1.f / 65536.f) - mu * mu;
    float sca = g[e] * rsqrtf(var + 1e-5f);
    sc[e] = sca;
    sh[e] = bb[e] - mu * sca;
  }
}

// finalize two ops in one tiny launch (partB at part+968)
__global__ void stats_final_dual(const float* __restrict__ part,
                                 const float* __restrict__ gA, const float* __restrict__ bA,
                                 float* __restrict__ scA, float* __restrict__ shA,
                                 const float* __restrict__ gB, const float* __restrict__ bB,
                                 float* __restrict__ scB, float* __restrict__ shB) {
  int t = threadIdx.x;
  if (t < 242) {
    int sel = t >= 121;
    int e = sel ? t - 121 : t;
    const float* pp = part + (sel ? 968 : 0);
    const float* g  = sel ? gB : gA;
    const float* bb = sel ? bB : bA;
    float* sc = sel ? scB : scA;
    float* sh = sel ? shB : shA;
    float s  = pp[e * 4] + pp[e * 4 + 1] + pp[e * 4 + 2] + pp[e * 4 + 3];
    float s2 = pp[484 + e * 4] + pp[484 + e * 4 + 1] +
               pp[484 + e * 4 + 2] + pp[484 + e * 4 + 3];
    float mu  = s  * (1.f / 65536.f);
    float var = s2 * (1.f / 65536.f) - mu * mu;
    float sca = g[e] * rsqrtf(var + 1e-5f);
    sc[e] = sca;
    sh[e] = bb[e] - mu * sca;
  }
}

// ------------------------------------------------------------------
// DUAL tconv1x1: two output ops sharing one input pass. 3-way p-split.
// ------------------------------------------------------------------
template<bool HASB, bool PRELU>
__global__ __launch_bounds__(256, 2)
void conv1x1_dual(const float* __restrict__ rA, const float* __restrict__ scA,
                  const float* __restrict__ shA,
                  const float* __restrict__ rB, const float* __restrict__ scB,
                  const float* __restrict__ shB,
                  const float* __restrict__ alpha_ptr, int alpha_idx,
                  const float* __restrict__ U1, const float* __restrict__ V1,
                  float* __restrict__ out1,
                  const float* __restrict__ U2, const float* __restrict__ V2,
                  float* __restrict__ out2) {
  __shared__ float su1[NPP * 11], su2[NPP * 11], sv1[121], sv2[121];
  __shared__ float sa[242], sb[242];
  int bid = blockIdx.x;
  int wg  = (bid & 7) * 96 + (bid >> 3);      // 768 % 8 == 0, bijective
  int part = wg % 3, posblk = wg / 3;
  int P0 = part * 4;
  int pmax = (part == 2) ? 3 : 4;
  int t = threadIdx.x;
  if (t < 121) {
    sv1[t] = V1[t]; sv2[t] = V2[t];
    sa[t] = scA[t]; sb[t] = shA[t];
    if (HASB) { sa[121 + t] = scB[t]; sb[121 + t] = shB[t]; }
  }
  if (t < NPP * 11) {
    int pr = t / 11, mm = t - pr * 11;
    int srow = P0 + pr; if (srow > 10) srow = 10;   // clamp dup row
    su1[t] = U1[srow * 11 + mm];
    su2[t] = U2[srow * 11 + mm];
  }
  __syncthreads();
  float alpha = 0.f;
  if (PRELU) alpha = alpha_ptr[alpha_idx];
  size_t pos = (size_t)posblk * 256 + t;

  float T1[NPP][11], T2[NPP][11];
#pragma unroll
  for (int p = 0; p < NPP; ++p)
#pragma unroll
    for (int n = 0; n < 11; ++n) { T1[p][n] = 0.f; T2[p][n] = 0.f; }

#pragma unroll 2
  for (int m = 0; m < 11; ++m) {
    float Xr[11];
#pragma unroll
    for (int n = 0; n < 11; ++n) {
      int e = m * 11 + n;
      float v = sa[e] * rA[(size_t)e * NPOS + pos] + sb[e];
      if (HASB) v += sa[121 + e] * rB[(size_t)e * NPOS + pos] + sb[121 + e];
      if (PRELU) v = v >= 0.f ? v : alpha * v;
      Xr[n] = v;
    }
#pragma unroll
    for (int p = 0; p < NPP; ++p) {
      float u1 = su1[p * 11 + m];
      float u2 = su2[p * 11 + m];
#pragma unroll
      for (int n = 0; n < 11; ++n) {
        T1[p][n] += u1 * Xr[n];
        T2[p][n] += u2 * Xr[n];
      }
    }
  }
#pragma unroll
  for (int q = 0; q < 11; ++q) {
    float Yc1[NPP], Yc2[NPP];
#pragma unroll
    for (int p = 0; p < NPP; ++p) { Yc1[p] = 0.f; Yc2[p] = 0.f; }
#pragma unroll
    for (int n = 0; n < 11; ++n) {
      float v1 = sv1[q * 11 + n];
      float v2 = sv2[q * 11 + n];
#pragma unroll
      for (int p = 0; p < NPP; ++p) {
        Yc1[p] += T1[p][n] * v1;
        Yc2[p] += T2[p][n] * v2;
      }
    }
    for (int p = 0; p < pmax; ++p) {          // pmax uniform per block
      out1[(size_t)((P0 + p) * 11 + q) * NPOS + pos] = Yc1[p];
      out2[(size_t)((P0 + p) * 11 + q) * NPOS + pos] = Yc2[p];
    }
  }
}

// ------------------------------------------------------------------
// single tconv1x1 (z2 -> z3), 2-way p-split. Grid 512.
// ------------------------------------------------------------------
template<bool HASB, bool PRELU>
__global__ __launch_bounds__(256, 2)
void conv1x1_kernel(const float* __restrict__ rA, const float* __restrict__ scA,
                    const float* __restrict__ shA,
                    const float* __restrict__ rB, const float* __restrict__ scB,
                    const float* __restrict__ shB,
                    const float* __restrict__ alpha_ptr, int alpha_idx,
                    const float* __restrict__ U, const float* __restrict__ V,
                    float* __restrict__ out) {
  __shared__ float su[NP * 11], sv[121], sa[242], sb[242];
  int bid = blockIdx.x;
  int wg  = (bid & 7) * 64 + (bid >> 3);
  int ph = wg & 1, posblk = wg >> 1;
  int P0 = ph * 5;
  int t = threadIdx.x;
  if (t < 121) {
    sv[t] = V[t];
    sa[t] = scA[t]; sb[t] = shA[t];
    if (HASB) { sa[121 + t] = scB[t]; sb[121 + t] = shB[t]; }
  }
  if (t < NP * 11) su[t] = U[P0 * 11 + t];
  __syncthreads();
  float alpha = 0.f;
  if (PRELU) alpha = alpha_ptr[alpha_idx];
  size_t pos = (size_t)posblk * 256 + t;

  float T[NP][11];
#pragma unroll
  for (int p = 0; p < NP; ++p)
#pragma unroll
    for (int n = 0; n < 11; ++n) T[p][n] = 0.f;

#pragma unroll 2
  for (int m = 0; m < 11; ++m) {
    float Xr[11];
#pragma unroll
    for (int n = 0; n < 11; ++n) {
      int e = m * 11 + n;
      float v = sa[e] * rA[(size_t)e * NPOS + pos] + sb[e];
      if (HASB) v += sa[121 + e] * rB[(size_t)e * NPOS + pos] + sb[121 + e];
      if (PRELU) v = v >= 0.f ? v : alpha * v;
      Xr[n] = v;
    }
#pragma unroll
    for (int p = 0; p < NP; ++p) {
      float u = su[p * 11 + m];
#pragma unroll
      for (int n = 0; n < 11; ++n) T[p][n] += u * Xr[n];
    }
  }
#pragma unroll
  for (int q = 0; q < 11; ++q) {
    float Yc[NP];
#pragma unroll
    for (int p = 0; p < NP; ++p) Yc[p] = 0.f;
#pragma unroll
    for (int n = 0; n < 11; ++n) {
      float v = sv[q * 11 + n];
#pragma unroll
      for (int p = 0; p < NP; ++p) Yc[p] += T[p][n] * v;
    }
#pragma unroll
    for (int p = 0; p < NP; ++p)
      out[(size_t)((P0 + p) * 11 + q) * NPOS + pos] = Yc[p];
  }
}

// ------------------------------------------------------------------
// tconv3x3, 2-way p-split. Grid 512.
// ------------------------------------------------------------------
template<int N0, int NW>
__device__ __forceinline__ void c3_chunk(const float* __restrict__ rA,
    const float* __restrict__ sa, const float* __restrict__ sh,
    const float* __restrict__ su, const float* __restrict__ sv,
    float alpha, int npos, float (&Y)[NP][11]) {
  float T[NP][NW];
#pragma unroll
  for (int p = 0; p < NP; ++p)
#pragma unroll
    for (int k = 0; k < NW; ++k) T[p][k] = 0.f;
#pragma unroll 2
  for (int m = 0; m < 11; ++m) {
    float Xr[NW];
#pragma unroll
    for (int k = 0; k < NW; ++k) {
      int e = m * 11 + N0 + k;
      float v = sa[e] * rA[(size_t)e * NPOS + npos] + sh[e];
      Xr[k] = v >= 0.f ? v : alpha * v;
    }
#pragma unroll
    for (int p = 0; p < NP; ++p) {
      float u = su[p * 11 + m];
#pragma unroll
      for (int k = 0; k < NW; ++k) T[p][k] += u * Xr[k];
    }
  }
#pragma unroll
  for (int k = 0; k < NW; ++k) {
#pragma unroll
    for (int q = 0; q < 11; ++q) {
      float v = sv[q * 11 + N0 + k];
#pragma unroll
      for (int p = 0; p < NP; ++p) Y[p][q] += T[p][k] * v;
    }
  }
}

__global__ __launch_bounds__(256, 2)
void conv3x3_kernel(const float* __restrict__ rA, const float* __restrict__ scA,
                    const float* __restrict__ shA,
                    const float* __restrict__ alpha_ptr, int alpha_idx,
                    const float* __restrict__ U, const float* __restrict__ V,
                    float* __restrict__ out) {
  __shared__ float su[9 * NP * 11], sv[1089], sa[121], sh[121];
  int bid = blockIdx.x;
  int wg  = (bid & 7) * 64 + (bid >> 3);
  int ph = wg & 1, posblk = wg >> 1;
  int P0 = ph * 5;
  int t = threadIdx.x;
  for (int idx = t; idx < 9 * NP * 11; idx += 256) {
    int ij = idx / (NP * 11), r = idx - ij * (NP * 11);
    su[idx] = U[ij * 121 + P0 * 11 + r];
  }
  for (int idx = t; idx < 1089; idx += 256) sv[idx] = V[idx];
  if (t < 121) { sa[t] = scA[t]; sh[t] = shA[t]; }
  __syncthreads();
  float alpha = alpha_ptr[alpha_idx];
  int pos = posblk * 256 + t;
  int b = pos >> 10, h = (pos >> 5) & 31, w = pos & 31;

  float Y[NP][11];
#pragma unroll
  for (int p = 0; p < NP; ++p)
#pragma unroll
    for (int q = 0; q < 11; ++q) Y[p][q] = 0.f;

  for (int ij = 0; ij < 9; ++ij) {
    int i = ij / 3, j = ij - 3 * (ij / 3);
    int hi = h + i - 1, wj = w + j - 1;
    if ((unsigned)hi >= 32u || (unsigned)wj >= 32u) continue;
    int npos = ((b << 5) + hi) * 32 + wj;
    const float* suij = &su[ij * NP * 11];
    const float* svij = &sv[ij * 121];
    c3_chunk<0, 4>(rA, sa, sh, suij, svij, alpha, npos, Y);
    c3_chunk<4, 4>(rA, sa, sh, suij, svij, alpha, npos, Y);
    c3_chunk<8, 3>(rA, sa, sh, suij, svij, alpha, npos, Y);
  }
#pragma unroll
  for (int p = 0; p < NP; ++p)
#pragma unroll
    for (int q = 0; q < 11; ++q)
      out[(size_t)((P0 + p) * 11 + q) * NPOS + pos] = Y[p][q];
}

// ------------------------------------------------------------------
// fcn head
// ------------------------------------------------------------------
__global__ __launch_bounds__(256, 2)
void head_kernel(const float* __restrict__ rA, const float* __restrict__ scA,
                 const float* __restrict__ shA,
                 const float* __restrict__ rB, const float* __restrict__ scB,
                 const float* __restrict__ shB,
                 const float* __restrict__ W, float* __restrict__ out) {
  __shared__ float sw[21 * 121], sa[242], sh[242];
  int t = threadIdx.x;
  for (int idx = t; idx < 2541; idx += 256) sw[idx] = W[idx];
  if (t < 121) {
    sa[t] = scA[t]; sh[t] = shA[t];
    sa[121 + t] = scB[t]; sh[121 + t] = shB[t];
  }
  __syncthreads();
  size_t pos = (size_t)blockIdx.x * 256 + t;
  int b = (int)(pos >> 10), hw = (int)(pos & 1023);
  float acc[21];
#pragma unroll
  for (int o = 0; o < 21; ++o) acc[o] = 0.f;
  for (int e = 0; e < 121; ++e) {
    float v = sa[e] * rA[(size_t)e * NPOS + pos] + sh[e] +
              sa[121 + e] * rB[(size_t)e * NPOS + pos] + sh[121 + e];
#pragma unroll
    for (int o = 0; o < 21; ++o) acc[o] += v * sw[o * 121 + e];
  }
#pragma unroll
  for (int o = 0; o < 21; ++o)
    out[(size_t)(b * 21 + o) * 1024 + hw] = acc[o];
}

// ------------------------------------------------------------------
extern "C" void kernel_launch(void* const* d_in, const int* in_sizes, int n_in,
                              void* d_out, int out_size, void* d_ws, size_t ws_size,
                              hipStream_t stream) {
  (void)in_sizes; (void)n_in; (void)out_size; (void)ws_size;
  const float* x     = (const float*)d_in[0];
  const float* f0_U  = (const float*)d_in[1];
  const float* f0_V  = (const float*)d_in[2];
  const float* f0_g  = (const float*)d_in[3];
  const float* f0_b  = (const float*)d_in[4];
  const float* f0_a  = (const float*)d_in[5];
  const float* s_U   = (const float*)d_in[6];
  const float* s_V   = (const float*)d_in[7];
  const float* s_g   = (const float*)d_in[8];
  const float* s_b   = (const float*)d_in[9];
  const float* bU1   = (const float*)d_in[10];
  const float* bV1   = (const float*)d_in[11];
  const float* bg1   = (const float*)d_in[12];
  const float* bb1   = (const float*)d_in[13];
  const float* ba1   = (const float*)d_in[14];
  const float* bU2   = (const float*)d_in[15];
  const float* bV2   = (const float*)d_in[16];
  const float* bg2   = (const float*)d_in[17];
  const float* bb2   = (const float*)d_in[18];
  const float* ba2   = (const float*)d_in[19];
  const float* bU3   = (const float*)d_in[20];
  const float* bV3   = (const float*)d_in[21];
  const float* bg3   = (const float*)d_in[22];
  const float* bb3   = (const float*)d_in[23];
  const float* headW = (const float*)d_in[24];

  float* ws = (float*)d_ws;
  const size_t BUF = (size_t)NE * NPOS;
  float* B[4]  = { ws, ws + BUF, ws + 2 * BUF, ws + 3 * BUF };
  float* st    = ws + 4 * BUF;              // 17 ops * (scale121 + shift121)
  float* psum  = st + 17 * 242;             // 121 * 2048 f0 row partials
  float* psq   = psum + 121 * 2048;
  float* part  = psq + 121 * 2048;          // 2 * 968 stats partials

  auto SCp = [&](int op) { return st + op * 242; };
  auto SHp = [&](int op) { return st + op * 242 + 121; };

  // ---- f0 (stats fused; finalize reduces row partials) ----
  f0_kernel<<<2048, 256, 0, stream>>>(x, f0_U, f0_V, B[0], psum, psq);
  f0_stats_final<<<121, 256, 0, stream>>>(psum, psq, f0_g, f0_b, SCp(0), SHp(0));

  const int bufs[4][4] = { {1,2,3,0}, {2,3,0,1}, {3,0,1,2}, {0,1,2,3} };

  const float* hA   = B[0];  const float* hAsc = SCp(0); const float* hAsh = SHp(0);
  const float* hB   = nullptr; const float* hBsc = nullptr; const float* hBsh = nullptr;

  for (int k = 0; k < 4; ++k) {
    float* idn = B[bufs[k][0]];
    float* z1  = B[bufs[k][1]];
    float* z2  = B[bufs[k][2]];
    float* z3  = B[bufs[k][3]];
    int op_idn = 1 + k * 4, op_z1 = 2 + k * 4, op_z2 = 3 + k * 4, op_z3 = 4 + k * 4;

    if (k == 0) {   // h0 = prelu(tbn(y)): single source + prelu; dual outputs
      conv1x1_dual<false, true><<<768, 256, 0, stream>>>(
          hA, hAsc, hAsh, nullptr, nullptr, nullptr, f0_a, 0,
          s_U + k * 121, s_V + k * 121, idn,
          bU1 + k * 121, bV1 + k * 121, z1);
    } else {        // h = tbn(z3_prev) + tbn(idn_prev): two sources, no prelu
      conv1x1_dual<true, false><<<768, 256, 0, stream>>>(
          hA, hAsc, hAsh, hB, hBsc, hBsh, nullptr, 0,
          s_U + k * 121, s_V + k * 121, idn,
          bU1 + k * 121, bV1 + k * 121, z1);
    }
    stats_partial<<<484, 256, 0, stream>>>(idn, part);
    stats_partial<<<484, 256, 0, stream>>>(z1, part + 968);
    stats_final_dual<<<1, 256, 0, stream>>>(
        part,
        s_g + k * 121, s_b + k * 121, SCp(op_idn), SHp(op_idn),
        bg1 + k * 121, bb1 + k * 121, SCp(op_z1),  SHp(op_z1));

    conv3x3_kernel<<<512, 256, 0, stream>>>(
        z1, SCp(op_z1), SHp(op_z1), ba1, k,
        bU2 + k * 1089, bV2 + k * 1089, z2);
    stats_partial<<<484, 256, 0, stream>>>(z2, part);
    stats_final<<<1, 128, 0, stream>>>(part, bg2 + k * 121, bb2 + k * 121,
                                       SCp(op_z2), SHp(op_z2));

    conv1x1_kernel<false, true><<<512, 256, 0, stream>>>(
        z2, SCp(op_z2), SHp(op_z2), nullptr, nullptr, nullptr, ba2, k,
        bU3 + k * 121, bV3 + k * 121, z3);
    stats_partial<<<484, 256, 0, stream>>>(z3, part);
    stats_final<<<1, 128, 0, stream>>>(part, bg3 + k * 121, bb3 + k * 121,
                                       SCp(op_z3), SHp(op_z3));

    hA = z3;  hAsc = SCp(op_z3);  hAsh = SHp(op_z3);
    hB = idn; hBsc = SCp(op_idn); hBsh = SHp(op_idn);
  }

  head_kernel<<<256, 256, 0, stream>>>(hA, hAsc, hAsh, hB, hBsc, hBsh,
                                       headW, (float*)d_out);
}

// Round 14
// 1639.649 us; speedup vs baseline: 1.2401x; 1.2401x over previous
//
#include <hip/hip_runtime.h>

#define NPOS 65536   // 64 batches * 32 * 32 positions
#define NE   121     // 11*11 tensor entries
#define NP   6       // p-rows per half (conv kernels + f0)
#define NPP  4       // p-rows per third for dual conv1x1 (4+4+3)

// direct HBM->LDS (no VGPR staging; dest = wave-uniform base + lane*16)
__device__ __forceinline__ void gload_lds16(const float* g, float* l) {
  __builtin_amdgcn_global_load_lds(
      (const __attribute__((address_space(1))) void*)g,
      (__attribute__((address_space(3))) void*)l, 16, 0, 0);
}

// finalize scale/shift from 968-float partial buffer (t<121 only)
__device__ __forceinline__ void fin_from_part(int e, const float* __restrict__ pp,
                                              const float* __restrict__ g,
                                              const float* __restrict__ bb,
                                              float& sc, float& sh) {
  float s  = pp[e * 4] + pp[e * 4 + 1] + pp[e * 4 + 2] + pp[e * 4 + 3];
  float s2 = pp[484 + e * 4] + pp[484 + e * 4 + 1] +
             pp[484 + e * 4 + 2] + pp[484 + e * 4 + 3];
  float mu  = s  * (1.f / 65536.f);
  float var = s2 * (1.f / 65536.f) - mu * mu;
  sc = g[e] * rsqrtf(var + 1e-5f);
  sh = bb[e] - mu * sc;
}

// ------------------------------------------------------------------
// f0 (R12-proven, ~1003us — FROZEN): 8-ch 3x3 tensorized conv + fused
// TBN partials. 2-way p-split, X slab dbuf via global_load_lds,
// U [tap][m][8] broadcasts. R9/R11/R13 lessons: global-U, xr+shfl,
// and full-Y variants all regress (latency / VGPR / occupancy cliff).
// ------------------------------------------------------------------
__global__ __launch_bounds__(256, 1)
void f0_kernel(const float* __restrict__ x, const float* __restrict__ U,
               const float* __restrict__ V, float* __restrict__ y,
               float* __restrict__ psum, float* __restrict__ psq) {
  __shared__ float Xb[16384];   // 2 x 8192 (64KB) double-buffered X slab
  __shared__ float su[1152];    // [tap][m][8]  : p-rows P0..P0+5 (+2 pad)
  __shared__ float sv[1728];    // [tap][n][12] : q 0..10 (+1 pad)

  int bid = blockIdx.x;
  int wg  = (bid & 7) * 512 + (bid >> 3);     // bijective, 4096 % 8 == 0
  int ph  = wg & 1;
  int row = wg >> 1;
  int b = row >> 5, h = row & 31;
  int P0 = ph * 5;
  int t = threadIdx.x;
  int s = t >> 5, w = t & 31;

  int hlo = (h == 0) ? 0 : h - 1;
  int hhi = (h == 31) ? 31 : h + 1;
  int nh = hhi - hlo + 1;
  int nslab = 8 * nh;

  float Y[NP][11];
#pragma unroll
  for (int p = 0; p < NP; ++p)
#pragma unroll
    for (int q = 0; q < 11; ++q) Y[p][q] = 0.f;

  auto stageUV = [&](int c) {
    for (int idx = t; idx < 1152; idx += 256) {     // su[tap*128 + m*8 + pr]
      int tap = idx >> 7, r = idx & 127;
      int m = r >> 3, pr = r & 7;
      su[idx] = (pr < 6) ? U[(c * 9 + tap) * 176 + (P0 + pr) * 16 + m] : 0.f;
    }
    for (int idx = t; idx < 1728; idx += 256) {     // sv[tap*192 + n*12 + q]
      int tap = idx / 192, r = idx - tap * 192;
      int n = r / 12, q = r - n * 12;
      sv[idx] = (q < 11) ? V[(c * 9 + tap) * 176 + q * 16 + n] : 0.f;
    }
  };

  auto issueX = [&](int k) {
    int c = k / nh, hi = hlo + k % nh;
    const float* base = x + ((size_t)(b * 8 + c) << 18) + hi * 32;
    float* buf = &Xb[(k & 1) * 8192];
    int wv = t >> 6, ln = t & 63;
#pragma unroll
    for (int kk = 0; kk < 8; ++kk) {
      int chunk = wv * 8 + kk;                      // wave-uniform
      int mn = chunk * 8 + (ln >> 3);
      gload_lds16(base + (size_t)mn * 1024 + (ln & 7) * 4, buf + chunk * 256);
    }
  };

  stageUV(0);
  issueX(0);

  for (int k = 0; k < nslab; ++k) {
    asm volatile("s_waitcnt vmcnt(0)" ::: "memory"); // slab k landed
    __syncthreads();
    if (k + 1 < nslab) issueX(k + 1);

    const float* Xt = &Xb[(k & 1) * 8192];
    int c = k / nh, hi = hlo + k % nh;
    int tapbase = (hi - h + 1) * 3;
#pragma unroll
    for (int j = 0; j < 3; ++j) {
      int wj = w + j - 1;
      if ((unsigned)wj < 32u) {
        int tap = tapbase + j;
        const float* suT = &su[tap * 128];
        const float* svT = &sv[tap * 192];
        float A0[6], A1[6];
#pragma unroll
        for (int p = 0; p < 6; ++p) { A0[p] = 0.f; A1[p] = 0.f; }
#pragma unroll
        for (int m = 0; m < 16; ++m) {
          float x0 = Xt[(m * 16 + 2 * s) * 32 + wj];
          float x1 = Xt[(m * 16 + 2 * s + 1) * 32 + wj];
          float4 u0 = *(const float4*)&suT[m * 8];       // broadcast
          float2 u1 = *(const float2*)&suT[m * 8 + 4];
          A0[0] += u0.x * x0; A1[0] += u0.x * x1;
          A0[1] += u0.y * x0; A1[1] += u0.y * x1;
          A0[2] += u0.z * x0; A1[2] += u0.z * x1;
          A0[3] += u0.w * x0; A1[3] += u0.w * x1;
          A0[4] += u1.x * x0; A1[4] += u1.x * x1;
          A0[5] += u1.y * x0; A1[5] += u1.y * x1;
        }
#pragma unroll
        for (int nn = 0; nn < 2; ++nn) {
          const float* vb = &svT[(2 * s + nn) * 12];
          float4 v0 = *(const float4*)&vb[0];
          float4 v1 = *(const float4*)&vb[4];
          float4 v2 = *(const float4*)&vb[8];
          float vq[11] = { v0.x, v0.y, v0.z, v0.w,
                           v1.x, v1.y, v1.z, v1.w,
                           v2.x, v2.y, v2.z };
          const float* Ax = nn ? A1 : A0;    // nn is unroll-static
#pragma unroll
          for (int p = 0; p < 6; ++p)
#pragma unroll
            for (int q = 0; q < 11; ++q)
              Y[p][q] += Ax[p] * vq[q];
        }
      }
    }
    if (k + 1 < nslab && (k % nh) == nh - 1) {    // next slab = new channel
      __syncthreads();
      stageUV(c + 1);
    }
  }

  // epilogue: reduce over s, write y, fused stats partials per (b,h) row
  int posb = ((b << 5) + h) << 5;
#pragma unroll
  for (int p = 0; p < NP; ++p) {
    __syncthreads();
#pragma unroll
    for (int q = 0; q < 11; ++q) Xb[t * 11 + q] = Y[p][q];
    __syncthreads();
    for (int rep = 0; rep < 2; ++rep) {
      int idx = rep * 256 + t;
      if (idx < 352) {                      // full 32-lane groups only
        int qq = idx >> 5, w2 = idx & 31;
        float v = 0.f;
#pragma unroll
        for (int s2 = 0; s2 < 8; ++s2) v += Xb[(s2 * 32 + w2) * 11 + qq];
        int e = (P0 + p) * 11 + qq;
        y[(size_t)e * NPOS + posb + w2] = v;
        float sm = v, sq = v * v;
#pragma unroll
        for (int d = 16; d > 0; d >>= 1) {
          sm += __shfl_down(sm, d, 32);
          sq += __shfl_down(sq, d, 32);
        }
        if (w2 == 0) {                      // ph overlap rows: bitwise-identical
          psum[(size_t)e * 2048 + row] = sm;
          psq [(size_t)e * 2048 + row] = sq;
        }
      }
    }
  }
}

// finalize f0 stats: 121 blocks sum 2048 row-partials -> scale/shift
__global__ __launch_bounds__(256)
void f0_stats_final(const float* __restrict__ psum, const float* __restrict__ psq,
                    const float* __restrict__ g, const float* __restrict__ bb,
                    float* __restrict__ sc, float* __restrict__ sh) {
  int e = blockIdx.x, t = threadIdx.x;
  float s = 0.f, s2 = 0.f;
  for (int i = t; i < 2048; i += 256) {
    s  += psum[(size_t)e * 2048 + i];
    s2 += psq [(size_t)e * 2048 + i];
  }
#pragma unroll
  for (int o = 32; o > 0; o >>= 1) {
    s  += __shfl_down(s, o);
    s2 += __shfl_down(s2, o);
  }
  __shared__ float ls[8];
  int wid = t >> 6;
  if ((t & 63) == 0) { ls[wid] = s; ls[4 + wid] = s2; }
  __syncthreads();
  if (t == 0) {
    float ss  = ls[0] + ls[1] + ls[2] + ls[3];
    float ss2 = ls[4] + ls[5] + ls[6] + ls[7];
    float mu  = ss  * (1.f / 65536.f);
    float var = ss2 * (1.f / 65536.f) - mu * mu;
    float sca = g[e] * rsqrtf(var + 1e-5f);
    sc[e] = sca;
    sh[e] = bb[e] - mu * sca;
  }
}

// ------------------------------------------------------------------
// stats partials: 484 blocks (single op) / 968 blocks (two ops).
// Finalization is inlined into the CONSUMER kernels (saves 12 tiny
// serial launches — R14 change).
// ------------------------------------------------------------------
__global__ __launch_bounds__(256)
void stats_partial(const float* __restrict__ raw, float* __restrict__ part) {
  int blk = blockIdx.x;
  int e = blk >> 2, qt = blk & 3;
  const float4* p = (const float4*)(raw + (size_t)e * NPOS) + qt * 4096;
  int t = threadIdx.x;
  float s = 0.f, s2 = 0.f;
  for (int i = t; i < 4096; i += 256) {
    float4 v = p[i];
    s  += v.x + v.y + v.z + v.w;
    s2 += v.x * v.x + v.y * v.y + v.z * v.z + v.w * v.w;
  }
#pragma unroll
  for (int o = 32; o > 0; o >>= 1) {
    s  += __shfl_down(s, o);
    s2 += __shfl_down(s2, o);
  }
  __shared__ float ls[8];
  int wid = t >> 6;
  if ((t & 63) == 0) { ls[wid] = s; ls[4 + wid] = s2; }
  __syncthreads();
  if (t == 0) {
    part[blk]       = ls[0] + ls[1] + ls[2] + ls[3];
    part[484 + blk] = ls[4] + ls[5] + ls[6] + ls[7];
  }
}

__global__ __launch_bounds__(256)
void stats_partial_dual(const float* __restrict__ rawA, float* __restrict__ partA,
                        const float* __restrict__ rawB, float* __restrict__ partB) {
  int blk = blockIdx.x;
  int sel = blk >= 484;
  int lblk = sel ? blk - 484 : blk;
  const float* raw = sel ? rawB : rawA;
  float* part = sel ? partB : partA;
  int e = lblk >> 2, qt = lblk & 3;
  const float4* p = (const float4*)(raw + (size_t)e * NPOS) + qt * 4096;
  int t = threadIdx.x;
  float s = 0.f, s2 = 0.f;
  for (int i = t; i < 4096; i += 256) {
    float4 v = p[i];
    s  += v.x + v.y + v.z + v.w;
    s2 += v.x * v.x + v.y * v.y + v.z * v.z + v.w * v.w;
  }
#pragma unroll
  for (int o = 32; o > 0; o >>= 1) {
    s  += __shfl_down(s, o);
    s2 += __shfl_down(s2, o);
  }
  __shared__ float ls[8];
  int wid = t >> 6;
  if ((t & 63) == 0) { ls[wid] = s; ls[4 + wid] = s2; }
  __syncthreads();
  if (t == 0) {
    part[lblk]       = ls[0] + ls[1] + ls[2] + ls[3];
    part[484 + lblk] = ls[4] + ls[5] + ls[6] + ls[7];
  }
}

// ------------------------------------------------------------------
// DUAL tconv1x1. FINA/FINB: finalize source stats from partials
// in-preamble (vs precomputed sc/sh). 3-way p-split.
// ------------------------------------------------------------------
template<bool HASB, bool PRELU, bool FINA, bool FINB>
__global__ __launch_bounds__(256, 2)
void conv1x1_dual(const float* __restrict__ rA,
                  const float* __restrict__ scA, const float* __restrict__ shA,
                  const float* __restrict__ pA, const float* __restrict__ gA,
                  const float* __restrict__ bA,
                  const float* __restrict__ rB,
                  const float* __restrict__ pB, const float* __restrict__ gB,
                  const float* __restrict__ bB,
                  const float* __restrict__ alpha_ptr, int alpha_idx,
                  const float* __restrict__ U1, const float* __restrict__ V1,
                  float* __restrict__ out1,
                  const float* __restrict__ U2, const float* __restrict__ V2,
                  float* __restrict__ out2) {
  __shared__ float su1[NPP * 11], su2[NPP * 11], sv1[121], sv2[121];
  __shared__ float sa[242], sb[242];
  int bid = blockIdx.x;
  int wg  = (bid & 7) * 96 + (bid >> 3);      // 768 % 8 == 0, bijective
  int part = wg % 3, posblk = wg / 3;
  int P0 = part * 4;
  int pmax = (part == 2) ? 3 : 4;
  int t = threadIdx.x;
  if (t < 121) {
    sv1[t] = V1[t]; sv2[t] = V2[t];
    if (FINA) fin_from_part(t, pA, gA, bA, sa[t], sb[t]);
    else      { sa[t] = scA[t]; sb[t] = shA[t]; }
    if (HASB) {
      if (FINB) fin_from_part(t, pB, gB, bB, sa[121 + t], sb[121 + t]);
    }
  }
  if (t < NPP * 11) {
    int pr = t / 11, mm = t - pr * 11;
    int srow = P0 + pr; if (srow > 10) srow = 10;   // clamp dup row
    su1[t] = U1[srow * 11 + mm];
    su2[t] = U2[srow * 11 + mm];
  }
  __syncthreads();
  float alpha = 0.f;
  if (PRELU) alpha = alpha_ptr[alpha_idx];
  size_t pos = (size_t)posblk * 256 + t;

  float T1[NPP][11], T2[NPP][11];
#pragma unroll
  for (int p = 0; p < NPP; ++p)
#pragma unroll
    for (int n = 0; n < 11; ++n) { T1[p][n] = 0.f; T2[p][n] = 0.f; }

#pragma unroll 2
  for (int m = 0; m < 11; ++m) {
    float Xr[11];
#pragma unroll
    for (int n = 0; n < 11; ++n) {
      int e = m * 11 + n;
      float v = sa[e] * rA[(size_t)e * NPOS + pos] + sb[e];
      if (HASB) v += sa[121 + e] * rB[(size_t)e * NPOS + pos] + sb[121 + e];
      if (PRELU) v = v >= 0.f ? v : alpha * v;
      Xr[n] = v;
    }
#pragma unroll
    for (int p = 0; p < NPP; ++p) {
      float u1 = su1[p * 11 + m];
      float u2 = su2[p * 11 + m];
#pragma unroll
      for (int n = 0; n < 11; ++n) {
        T1[p][n] += u1 * Xr[n];
        T2[p][n] += u2 * Xr[n];
      }
    }
  }
#pragma unroll
  for (int q = 0; q < 11; ++q) {
    float Yc1[NPP], Yc2[NPP];
#pragma unroll
    for (int p = 0; p < NPP; ++p) { Yc1[p] = 0.f; Yc2[p] = 0.f; }
#pragma unroll
    for (int n = 0; n < 11; ++n) {
      float v1 = sv1[q * 11 + n];
      float v2 = sv2[q * 11 + n];
#pragma unroll
      for (int p = 0; p < NPP; ++p) {
        Yc1[p] += T1[p][n] * v1;
        Yc2[p] += T2[p][n] * v2;
      }
    }
    for (int p = 0; p < pmax; ++p) {          // pmax uniform per block
      out1[(size_t)((P0 + p) * 11 + q) * NPOS + pos] = Yc1[p];
      out2[(size_t)((P0 + p) * 11 + q) * NPOS + pos] = Yc2[p];
    }
  }
}

// ------------------------------------------------------------------
// single tconv1x1 (z2 -> z3), 2-way p-split, stats finalized inline.
// ------------------------------------------------------------------
template<bool PRELU>
__global__ __launch_bounds__(256, 2)
void conv1x1_kernel(const float* __restrict__ rA,
                    const float* __restrict__ pA, const float* __restrict__ gA,
                    const float* __restrict__ bA,
                    const float* __restrict__ alpha_ptr, int alpha_idx,
                    const float* __restrict__ U, const float* __restrict__ V,
                    float* __restrict__ out) {
  __shared__ float su[NP * 11], sv[121], sa[242], sb[242];
  int bid = blockIdx.x;
  int wg  = (bid & 7) * 64 + (bid >> 3);
  int ph = wg & 1, posblk = wg >> 1;
  int P0 = ph * 5;
  int t = threadIdx.x;
  if (t < 121) {
    sv[t] = V[t];
    fin_from_part(t, pA, gA, bA, sa[t], sb[t]);
  }
  if (t < NP * 11) su[t] = U[P0 * 11 + t];
  __syncthreads();
  float alpha = 0.f;
  if (PRELU) alpha = alpha_ptr[alpha_idx];
  size_t pos = (size_t)posblk * 256 + t;

  float T[NP][11];
#pragma unroll
  for (int p = 0; p < NP; ++p)
#pragma unroll
    for (int n = 0; n < 11; ++n) T[p][n] = 0.f;

#pragma unroll 2
  for (int m = 0; m < 11; ++m) {
    float Xr[11];
#pragma unroll
    for (int n = 0; n < 11; ++n) {
      int e = m * 11 + n;
      float v = sa[e] * rA[(size_t)e * NPOS + pos] + sb[e];
      if (PRELU) v = v >= 0.f ? v : alpha * v;
      Xr[n] = v;
    }
#pragma unroll
    for (int p = 0; p < NP; ++p) {
      float u = su[p * 11 + m];
#pragma unroll
      for (int n = 0; n < 11; ++n) T[p][n] += u * Xr[n];
    }
  }
#pragma unroll
  for (int q = 0; q < 11; ++q) {
    float Yc[NP];
#pragma unroll
    for (int p = 0; p < NP; ++p) Yc[p] = 0.f;
#pragma unroll
    for (int n = 0; n < 11; ++n) {
      float v = sv[q * 11 + n];
#pragma unroll
      for (int p = 0; p < NP; ++p) Yc[p] += T[p][n] * v;
    }
#pragma unroll
    for (int p = 0; p < NP; ++p)
      out[(size_t)((P0 + p) * 11 + q) * NPOS + pos] = Yc[p];
  }
}

// ------------------------------------------------------------------
// tconv3x3, 2-way p-split, stats finalized inline. Grid 512.
// ------------------------------------------------------------------
template<int N0, int NW>
__device__ __forceinline__ void c3_chunk(const float* __restrict__ rA,
    const float* __restrict__ sa, const float* __restrict__ sh,
    const float* __restrict__ su, const float* __restrict__ sv,
    float alpha, int npos, float (&Y)[NP][11]) {
  float T[NP][NW];
#pragma unroll
  for (int p = 0; p < NP; ++p)
#pragma unroll
    for (int k = 0; k < NW; ++k) T[p][k] = 0.f;
#pragma unroll 2
  for (int m = 0; m < 11; ++m) {
    float Xr[NW];
#pragma unroll
    for (int k = 0; k < NW; ++k) {
      int e = m * 11 + N0 + k;
      float v = sa[e] * rA[(size_t)e * NPOS + npos] + sh[e];
      Xr[k] = v >= 0.f ? v : alpha * v;
    }
#pragma unroll
    for (int p = 0; p < NP; ++p) {
      float u = su[p * 11 + m];
#pragma unroll
      for (int k = 0; k < NW; ++k) T[p][k] += u * Xr[k];
    }
  }
#pragma unroll
  for (int k = 0; k < NW; ++k) {
#pragma unroll
    for (int q = 0; q < 11; ++q) {
      float v = sv[q * 11 + N0 + k];
#pragma unroll
      for (int p = 0; p < NP; ++p) Y[p][q] += T[p][k] * v;
    }
  }
}

__global__ __launch_bounds__(256, 2)
void conv3x3_kernel(const float* __restrict__ rA,
                    const float* __restrict__ pA, const float* __restrict__ gA,
                    const float* __restrict__ bA,
                    const float* __restrict__ alpha_ptr, int alpha_idx,
                    const float* __restrict__ U, const float* __restrict__ V,
                    float* __restrict__ out) {
  __shared__ float su[9 * NP * 11], sv[1089], sa[121], sh[121];
  int bid = blockIdx.x;
  int wg  = (bid & 7) * 64 + (bid >> 3);
  int ph = wg & 1, posblk = wg >> 1;
  int P0 = ph * 5;
  int t = threadIdx.x;
  for (int idx = t; idx < 9 * NP * 11; idx += 256) {
    int ij = idx / (NP * 11), r = idx - ij * (NP * 11);
    su[idx] = U[ij * 121 + P0 * 11 + r];
  }
  for (int idx = t; idx < 1089; idx += 256) sv[idx] = V[idx];
  if (t < 121) fin_from_part(t, pA, gA, bA, sa[t], sh[t]);
  __syncthreads();
  float alpha = alpha_ptr[alpha_idx];
  int pos = posblk * 256 + t;
  int b = pos >> 10, h = (pos >> 5) & 31, w = pos & 31;

  float Y[NP][11];
#pragma unroll
  for (int p = 0; p < NP; ++p)
#pragma unroll
    for (int q = 0; q < 11; ++q) Y[p][q] = 0.f;

  for (int ij = 0; ij < 9; ++ij) {
    int i = ij / 3, j = ij - 3 * (ij / 3);
    int hi = h + i - 1, wj = w + j - 1;
    if ((unsigned)hi >= 32u || (unsigned)wj >= 32u) continue;
    int npos = ((b << 5) + hi) * 32 + wj;
    const float* suij = &su[ij * NP * 11];
    const float* svij = &sv[ij * 121];
    c3_chunk<0, 4>(rA, sa, sh, suij, svij, alpha, npos, Y);
    c3_chunk<4, 4>(rA, sa, sh, suij, svij, alpha, npos, Y);
    c3_chunk<8, 3>(rA, sa, sh, suij, svij, alpha, npos, Y);
  }
#pragma unroll
  for (int p = 0; p < NP; ++p)
#pragma unroll
    for (int q = 0; q < 11; ++q)
      out[(size_t)((P0 + p) * 11 + q) * NPOS + pos] = Y[p][q];
}

// ------------------------------------------------------------------
// fcn head: both sources finalized inline from partials.
// ------------------------------------------------------------------
__global__ __launch_bounds__(256, 2)
void head_kernel(const float* __restrict__ rA,
                 const float* __restrict__ pA, const float* __restrict__ gA,
                 const float* __restrict__ bA,
                 const float* __restrict__ rB,
                 const float* __restrict__ pB, const float* __restrict__ gB,
                 const float* __restrict__ bB,
                 const float* __restrict__ W, float* __restrict__ out) {
  __shared__ float sw[21 * 121], sa[242], sh[242];
  int t = threadIdx.x;
  for (int idx = t; idx < 2541; idx += 256) sw[idx] = W[idx];
  if (t < 121) {
    fin_from_part(t, pA, gA, bA, sa[t], sh[t]);
    fin_from_part(t, pB, gB, bB, sa[121 + t], sh[121 + t]);
  }
  __syncthreads();
  size_t pos = (size_t)blockIdx.x * 256 + t;
  int b = (int)(pos >> 10), hw = (int)(pos & 1023);
  float acc[21];
#pragma unroll
  for (int o = 0; o < 21; ++o) acc[o] = 0.f;
  for (int e = 0; e < 121; ++e) {
    float v = sa[e] * rA[(size_t)e * NPOS + pos] + sh[e] +
              sa[121 + e] * rB[(size_t)e * NPOS + pos] + sh[121 + e];
#pragma unroll
    for (int o = 0; o < 21; ++o) acc[o] += v * sw[o * 121 + e];
  }
#pragma unroll
  for (int o = 0; o < 21; ++o)
    out[(size_t)(b * 21 + o) * 1024 + hw] = acc[o];
}

// ------------------------------------------------------------------
extern "C" void kernel_launch(void* const* d_in, const int* in_sizes, int n_in,
                              void* d_out, int out_size, void* d_ws, size_t ws_size,
                              hipStream_t stream) {
  (void)in_sizes; (void)n_in; (void)out_size; (void)ws_size;
  const float* x     = (const float*)d_in[0];
  const float* f0_U  = (const float*)d_in[1];
  const float* f0_V  = (const float*)d_in[2];
  const float* f0_g  = (const float*)d_in[3];
  const float* f0_b  = (const float*)d_in[4];
  const float* f0_a  = (const float*)d_in[5];
  const float* s_U   = (const float*)d_in[6];
  const float* s_V   = (const float*)d_in[7];
  const float* s_g   = (const float*)d_in[8];
  const float* s_b   = (const float*)d_in[9];
  const float* bU1   = (const float*)d_in[10];
  const float* bV1   = (const float*)d_in[11];
  const float* bg1   = (const float*)d_in[12];
  const float* bb1   = (const float*)d_in[13];
  const float* ba1   = (const float*)d_in[14];
  const float* bU2   = (const float*)d_in[15];
  const float* bV2   = (const float*)d_in[16];
  const float* bg2   = (const float*)d_in[17];
  const float* bb2   = (const float*)d_in[18];
  const float* ba2   = (const float*)d_in[19];
  const float* bU3   = (const float*)d_in[20];
  const float* bV3   = (const float*)d_in[21];
  const float* bg3   = (const float*)d_in[22];
  const float* bb3   = (const float*)d_in[23];
  const float* headW = (const float*)d_in[24];

  float* ws = (float*)d_ws;
  const size_t BUF = (size_t)NE * NPOS;
  float* B[4]  = { ws, ws + BUF, ws + 2 * BUF, ws + 3 * BUF };
  float* st    = ws + 4 * BUF;              // sc/sh for f0 (242 floats)
  float* psum  = st + 242;                  // 121 * 2048 f0 row partials
  float* psq   = psum + 121 * 2048;
  float* pb0   = psq + 121 * 2048;          // idn partials (968)
  float* pb1   = pb0 + 968;                 // z1 partials
  float* pb2   = pb1 + 968;                 // z2 partials
  float* pb3   = pb2 + 968;                 // z3 partials

  // ---- f0 (stats fused; finalize reduces row partials) ----
  f0_kernel<<<4096, 256, 0, stream>>>(x, f0_U, f0_V, B[0], psum, psq);
  f0_stats_final<<<121, 256, 0, stream>>>(psum, psq, f0_g, f0_b, st, st + 121);

  const int bufs[4][4] = { {1,2,3,0}, {2,3,0,1}, {3,0,1,2}, {0,1,2,3} };

  const float* hA = B[0];   // z3(k-1) for k>0; f0 out for k=0
  const float* hB = nullptr;

  for (int k = 0; k < 4; ++k) {
    float* idn = B[bufs[k][0]];
    float* z1  = B[bufs[k][1]];
    float* z2  = B[bufs[k][2]];
    float* z3  = B[bufs[k][3]];

    if (k == 0) {   // h0 = prelu(tbn(y)): sc/sh precomputed; prelu; no B
      conv1x1_dual<false, true, false, false><<<768, 256, 0, stream>>>(
          hA, st, st + 121, nullptr, nullptr, nullptr,
          nullptr, nullptr, nullptr, nullptr,
          f0_a, 0,
          s_U + k * 121, s_V + k * 121, idn,
          bU1 + k * 121, bV1 + k * 121, z1);
    } else {        // h = tbn(z3_prev) + tbn(idn_prev): finalize from pb3/pb0
      conv1x1_dual<true, false, true, true><<<768, 256, 0, stream>>>(
          hA, nullptr, nullptr, pb3, bg3 + (k - 1) * 121, bb3 + (k - 1) * 121,
          hB, pb0, s_g + (k - 1) * 121, s_b + (k - 1) * 121,
          nullptr, 0,
          s_U + k * 121, s_V + k * 121, idn,
          bU1 + k * 121, bV1 + k * 121, z1);
    }
    stats_partial_dual<<<968, 256, 0, stream>>>(idn, pb0, z1, pb1);

    conv3x3_kernel<<<512, 256, 0, stream>>>(
        z1, pb1, bg1 + k * 121, bb1 + k * 121, ba1, k,
        bU2 + k * 1089, bV2 + k * 1089, z2);
    stats_partial<<<484, 256, 0, stream>>>(z2, pb2);

    conv1x1_kernel<true><<<512, 256, 0, stream>>>(
        z2, pb2, bg2 + k * 121, bb2 + k * 121, ba2, k,
        bU3 + k * 121, bV3 + k * 121, z3);
    stats_partial<<<484, 256, 0, stream>>>(z3, pb3);

    hA = z3;
    hB = idn;
  }

  head_kernel<<<256, 256, 0, stream>>>(
      hA, pb3, bg3 + 3 * 121, bb3 + 3 * 121,
      hB, pb0, s_g + 3 * 121, s_b + 3 * 121,
      headW, (float*)d_out);
}